// Round 4
// baseline (105.080 us; speedup 1.0000x reference)
//
#include <hip/hip_runtime.h>
#include <math.h>

#define C_IN  128
#define H_IN  56
#define W_IN  56
#define N_IN  8
#define O_MID 64
#define KK    5
#define NCLS  2

// ws layout (floats):
//   [0, 7680)        Weff[5][128][12]  (slots 0..9 = [dj][k], 10,11 pad)
//   [7680, 7682)     beff[2]
//   [7684, 7684+50176*20)  part[idx][di][4]  idx=((n*49+tile)*64+px)*2+k
#define WEFF_STRIDE 12
#define WEFF_SIZE   (5 * C_IN * WEFF_STRIDE)
#define PART_BASE   7684
#define N_IDX       (N_IN * 49 * 64 * NCLS)   // 50176

// 50 blocks: b = p*2 + k. 256 threads: c = t&127, o-half = t>>7.
__global__ __launch_bounds__(256) void k_weff(const float* __restrict__ Wt,
                                              const float* __restrict__ bias,
                                              const float* __restrict__ Wlin,
                                              const float* __restrict__ blin,
                                              float* __restrict__ ws) {
    const int b = blockIdx.x;
    const int p = b >> 1;
    const int k = b & 1;
    const int t = threadIdx.x;
    const int c = t & 127;
    const int oh = t >> 7;
    float s = 0.f;
#pragma unroll
    for (int oo = 0; oo < 32; ++oo) {
        const int o = oh * 32 + oo;
        s += Wlin[k * O_MID + o] * Wt[(o * C_IN + c) * (KK * KK) + p];
    }
    __shared__ float part[256];
    part[t] = s;
    __syncthreads();
    if (t < 128) {
        const int di = p / KK;
        const int dj = p - di * KK;
        ws[(di * C_IN + c) * WEFF_STRIDE + dj * 2 + k] = part[c] + part[c + 128];
    }
    if (p == 0 && t < 64) {
        float v = Wlin[k * O_MID + t] * bias[t];
#pragma unroll
        for (int off = 32; off; off >>= 1) v += __shfl_down(v, off, 64);
        if (t == 0) ws[WEFF_SIZE + k] = v + blin[k];
    }
}

// Split-di: block = (tile_x, tile_y, n*5+di). 256 thr = 4 waves.
// Lane: strip=lane&15 (sy=strip>>1, sx0=(strip&1)*4, px=strip*4+j), cq=lane>>4.
// Channel split 16-way: c = (w*4+cq) + 16*ii + 32*cc  (w=wave, ii=0..1, cc chunk).
// Halo per channel: 8 rows x 12 cols (row = sy, since block rows pre-offset by di).
#define CHUNK_C   32
#define N_CHUNK   4
#define CH_PAD    104                       // padded channel stride (dwords); 104%32=8
#define HALO_EL   96                        // 8*12 payload per channel
#define CHUNK_EL  (CHUNK_C * HALO_EL)       // 3072
#define LD_PT     (CHUNK_EL / 256)          // 12 loads/thread/chunk
#define RED_STRIDE 42

__global__ __launch_bounds__(256) void k_part(const float* __restrict__ x,
                                              const float* __restrict__ ws,
                                              float* __restrict__ part_out) {
    __shared__ float xs[2][CHUNK_C * CH_PAD];   // 2 x 13312 B
    __shared__ float wsh[C_IN * WEFF_STRIDE];   // 6144 B  (Weff[di] slice)
    float* red = &xs[0][0];                     // aliased after loop: 64*42 floats

    const int tid   = threadIdx.x;
    const int w     = tid >> 6;
    const int lane  = tid & 63;
    const int strip = lane & 15;
    const int cq    = lane >> 4;
    const int sy    = strip >> 1;
    const int sx0   = (strip & 1) << 2;
    const int x0g   = blockIdx.x * 8;
    const int y0g   = blockIdx.y * 8;
    const int z     = blockIdx.z;
    const int n     = z / 5;
    const int di    = z - n * 5;

    // stage this di's Weff slice into LDS
    const float* wsrc = ws + di * (C_IN * WEFF_STRIDE);
    for (int i = tid; i < C_IN * WEFF_STRIDE; i += 256) wsh[i] = wsrc[i];
    const float b0 = ws[WEFF_SIZE + 0];
    const float b1 = ws[WEFF_SIZE + 1];

    const float* xn = x + (size_t)n * (C_IN * H_IN * W_IN);
    const int y0base = y0g + di - 2;            // first halo row (global)

    // per-thread staging addresses (12 elements/thread/chunk)
    int goff[LD_PT];   // chunk-0 global offset, -1 = zero-fill
    int widx[LD_PT];   // padded LDS index
#pragma unroll
    for (int j = 0; j < LD_PT; ++j) {
        const int i   = tid + 256 * j;          // 0..3071
        const int c   = i / HALO_EL;
        const int r   = i - c * HALO_EL;
        const int row = r / 12;
        const int col = r - row * 12;
        const int gy  = y0base + row;
        const int gx  = x0g + col - 2;
        widx[j] = c * CH_PAD + r;
        goff[j] = ((unsigned)gy < H_IN && (unsigned)gx < W_IN)
                      ? (c * (H_IN * W_IN) + gy * W_IN + gx) : -1;
    }

    // stage chunk 0
    {
        float pf[LD_PT];
#pragma unroll
        for (int j = 0; j < LD_PT; ++j) pf[j] = (goff[j] >= 0) ? xn[goff[j]] : 0.f;
#pragma unroll
        for (int j = 0; j < LD_PT; ++j) xs[0][widx[j]] = pf[j];
    }
    __syncthreads();

    float acc[5][2][4];
#pragma unroll
    for (int a = 0; a < 5; ++a)
#pragma unroll
        for (int b = 0; b < 2; ++b)
#pragma unroll
            for (int j = 0; j < 4; ++j) acc[a][b][j] = 0.f;

    const int rbase = sy * 12 + sx0;
    const int w4cq  = w * 4 + cq;

    for (int cc = 0; cc < N_CHUNK; ++cc) {
        float* cur = xs[cc & 1];
        float* nxt = xs[(cc & 1) ^ 1];
        float pf[LD_PT];
        if (cc < N_CHUNK - 1) {
            const int cofs = (cc + 1) * CHUNK_C * (H_IN * W_IN);
#pragma unroll
            for (int j = 0; j < LD_PT; ++j)
                pf[j] = (goff[j] >= 0) ? xn[cofs + goff[j]] : 0.f;
        }
#pragma unroll
        for (int ii = 0; ii < 2; ++ii) {
            const int cl = w4cq + (ii << 4);            // 0..31
            const int cg = cc * CHUNK_C + cl;           // 0..127
            const float4 xa = *(const float4*)&cur[cl * CH_PAD + rbase];
            const float4 xb = *(const float4*)&cur[cl * CH_PAD + rbase + 4];
            const float xr[8] = {xa.x, xa.y, xa.z, xa.w, xb.x, xb.y, xb.z, xb.w};
            const float* wp = &wsh[cg * WEFF_STRIDE];
            const float4 wa = *(const float4*)(wp);
            const float4 wb = *(const float4*)(wp + 4);
            const float2 wc = *(const float2*)(wp + 8);
            const float wv[10] = {wa.x, wa.y, wa.z, wa.w,
                                  wb.x, wb.y, wb.z, wb.w, wc.x, wc.y};
#pragma unroll
            for (int dj = 0; dj < 5; ++dj)
#pragma unroll
                for (int j = 0; j < 4; ++j) {
                    const float xv = xr[dj + j];
                    acc[dj][0][j] = fmaf(xv, wv[dj * 2 + 0], acc[dj][0][j]);
                    acc[dj][1][j] = fmaf(xv, wv[dj * 2 + 1], acc[dj][1][j]);
                }
        }
        if (cc < N_CHUNK - 1) {
#pragma unroll
            for (int j = 0; j < LD_PT; ++j) nxt[widx[j]] = pf[j];
        }
        __syncthreads();
    }

    // reduce across cq (lane bits 4,5)
#pragma unroll
    for (int a = 0; a < 5; ++a)
#pragma unroll
        for (int b = 0; b < 2; ++b)
#pragma unroll
            for (int j = 0; j < 4; ++j) {
                float v = acc[a][b][j];
                v += __shfl_xor(v, 16, 64);
                v += __shfl_xor(v, 32, 64);
                acc[a][b][j] = v;
            }

    // cross-wave reduction staging (xs free after loop-exit barrier)
    if (cq == 0) {
        const int g = w * 16 + strip;
        float* rp = &red[g * RED_STRIDE];
#pragma unroll
        for (int a = 0; a < 5; ++a)
#pragma unroll
            for (int b = 0; b < 2; ++b)
#pragma unroll
                for (int j = 0; j < 4; ++j) rp[(a * 2 + b) * 4 + j] = acc[a][b][j];
    }
    __syncthreads();

    if (tid < 128) {
        const int px = tid >> 1;                // 0..63
        const int k  = tid & 1;
        const int st = px >> 2;                 // strip
        const int j  = px & 3;
        const float be = k ? b1 : b0;
        float A = 0.f, X = 0.f, Cs = 0.f;
#pragma unroll
        for (int dj = 0; dj < 5; ++dj) {
            float v = 0.f;
#pragma unroll
            for (int ww = 0; ww < 4; ++ww)
                v += red[(ww * 16 + st) * RED_STRIDE + (dj * 2 + k) * 4 + j];
            v += be;
            const float av = fabsf(v);
            A  += av;
            X  += av * (float)(dj - 2);
            Cs += v;
        }
        const int tile = blockIdx.y * 7 + blockIdx.x;
        const int idx  = ((n * 49 + tile) * 64 + px) * 2 + k;
        float4 st4 = make_float4(A, X, Cs, A * (float)(di - 2));
        *(float4*)&part_out[(size_t)idx * 20 + di * 4] = st4;
    }
}

__global__ __launch_bounds__(256) void k_comb(const float* __restrict__ part,
                                              float* __restrict__ out) {
    const int idx = blockIdx.x * 256 + threadIdx.x;   // 0..50175
    const float4 p0 = *(const float4*)&part[(size_t)idx * 20 + 0];
    const float4 p1 = *(const float4*)&part[(size_t)idx * 20 + 4];
    const float4 p2 = *(const float4*)&part[(size_t)idx * 20 + 8];
    const float4 p3 = *(const float4*)&part[(size_t)idx * 20 + 12];
    const float4 p4 = *(const float4*)&part[(size_t)idx * 20 + 16];
    const float A  = p0.x + p1.x + p2.x + p3.x + p4.x;
    const float X  = p0.y + p1.y + p2.y + p3.y + p4.y;
    const float Cs = p0.z + p1.z + p2.z + p3.z + p4.z;
    const float Y  = p0.w + p1.w + p2.w + p3.w + p4.w;
    const float xd = X / A;
    const float yd = Y / A;
    const float drift = sqrtf(xd * xd + yd * yd);
    const float o = Cs * expf(-0.5f * drift);

    const int k  = idx & 1;
    const int px = (idx >> 1) & 63;
    const int q  = idx >> 7;                  // n*49 + tile
    const int n  = q / 49;
    const int tile = q - n * 49;
    const int gy = (tile / 7) * 8 + (px >> 3);
    const int gx = (tile % 7) * 8 + (px & 7);
    out[((size_t)(n * H_IN + gy) * W_IN + gx) * NCLS + k] = o;
}

extern "C" void kernel_launch(void* const* d_in, const int* in_sizes, int n_in,
                              void* d_out, int out_size, void* d_ws, size_t ws_size,
                              hipStream_t stream) {
    const float* x    = (const float*)d_in[0];
    const float* Wt   = (const float*)d_in[1];
    const float* bias = (const float*)d_in[2];
    const float* Wlin = (const float*)d_in[3];
    const float* blin = (const float*)d_in[4];
    float* ws = (float*)d_ws;

    k_weff<<<dim3(KK * KK * NCLS), dim3(256), 0, stream>>>(Wt, bias, Wlin, blin, ws);
    k_part<<<dim3(7, 7, N_IN * KK), dim3(256), 0, stream>>>(x, ws, ws + PART_BASE);
    k_comb<<<dim3(N_IDX / 256), dim3(256), 0, stream>>>(ws + PART_BASE, (float*)d_out);
}